// Round 10
// baseline (262.075 us; speedup 1.0000x reference)
//
#include <hip/hip_runtime.h>

// 2-layer GCN on MI355X — gather formulation, two-level counting sort,
// dis-prescaled bf16 features, tiled layer-1 GEMM, and a fused
// gather + in-wave 64x32 GEMM for layer 2 (no separate gemm32 kernel).
//
// out = relu(Ahat @ relu(Ahat @ (x@W1) + b1) @ W2 + b2),
// Ahat = D^-1/2 (A+I) D^-1/2.
//
// Pipeline:
//  1. counting sort (packed uint pairs) -> off[], dis[], ssrc[]
//  2. k_gemm64t    : h1b = bf16( dis ⊙ (x @ W1) )        [tiled 8x8/thread]
//  3. k_gathergemm : p = relu(dis[i]*(Σ h1b[src] + h1b[i]) + b1)  (in-reg)
//                    h2b = bf16( dis[i] * (p @ W2) )     [in-wave GEMM]
//  4. k_gather32v  : out = relu(dis[i]*(Σ h2b[src] + h2b[i]) + b2)  (f32)

#define NBMAX 512  // coarse buckets (dst>>8); requires n < 2^17

// ---- bf16 pack/unpack (round-to-nearest-even) ----
__device__ __forceinline__ unsigned bf16pair(float a, float b) {
  unsigned ua = __float_as_uint(a), ub = __float_as_uint(b);
  ua = (ua + 0x7fffu + ((ua >> 16) & 1u)) >> 16;
  ub = (ub + 0x7fffu + ((ub >> 16) & 1u)) >> 16;
  return ua | (ub << 16);
}
__device__ __forceinline__ float bf_lo(unsigned v) { return __uint_as_float(v << 16); }
__device__ __forceinline__ float bf_hi(unsigned v) { return __uint_as_float(v & 0xffff0000u); }

// ---------------- sort pipeline ----------------

__global__ __launch_bounds__(256) void k_coarsehist(const int* __restrict__ dst,
                                                    int* __restrict__ ch,
                                                    int E, int NB) {
  __shared__ int lh[NBMAX];
  int t = threadIdx.x;
  lh[t] = 0; lh[t + 256] = 0;
  __syncthreads();
  for (int e = blockIdx.x * 256 + t; e < E; e += gridDim.x * 256)
    atomicAdd(&lh[dst[e] >> 8], 1);
  __syncthreads();
  for (int b = t; b < NB; b += 256) {
    int c = lh[b];
    if (c) atomicAdd(&ch[b], c);
  }
}

__global__ __launch_bounds__(512) void k_scanb(const int* __restrict__ ch,
                                               int* __restrict__ cbase,
                                               int* __restrict__ gcur,
                                               int* __restrict__ off,
                                               int NB, int n, int E) {
  __shared__ int lds[512];
  int t = threadIdx.x;
  int v = (t < NB) ? ch[t] : 0;
  lds[t] = v;
  __syncthreads();
  for (int d = 1; d < 512; d <<= 1) {
    int u = (t >= d) ? lds[t - d] : 0;
    __syncthreads();
    lds[t] += u;
    __syncthreads();
  }
  if (t < NB) {
    int exc = lds[t] - v;
    cbase[t] = exc;
    gcur[t]  = exc;
  }
  if (t == 0) off[n] = E;
}

// Tile-phased binning: packed (src<<8 | dst&255) runs per coarse bucket.
#define BIN_TILE 8192
__global__ __launch_bounds__(256) void k_binpairs(const int* __restrict__ src,
                                                  const int* __restrict__ dst,
                                                  int* __restrict__ gcur,
                                                  unsigned* __restrict__ pairs,
                                                  int E, int NB) {
  __shared__ int lcnt[NBMAX], gbase[NBMAX];
  int t = threadIdx.x;
  int tile0 = blockIdx.x * BIN_TILE;
  lcnt[t] = 0; lcnt[t + 256] = 0;
  __syncthreads();
#pragma unroll
  for (int j = 0; j < BIN_TILE / 256; ++j) {
    int e = tile0 + j * 256 + t;
    if (e < E) atomicAdd(&lcnt[dst[e] >> 8], 1);
  }
  __syncthreads();
  for (int b = t; b < NB; b += 256) {
    int c = lcnt[b];
    if (c) gbase[b] = atomicAdd(&gcur[b], c);
    lcnt[b] = 0;
  }
  __syncthreads();
#pragma unroll
  for (int j = 0; j < BIN_TILE / 256; ++j) {
    int e = tile0 + j * 256 + t;
    if (e < E) {
      int dv = dst[e];
      int b  = dv >> 8;
      int slot = atomicAdd(&lcnt[b], 1);
      pairs[gbase[b] + slot] = ((unsigned)src[e] << 8) | (unsigned)(dv & 255);
    }
  }
}

// One block (512 thr) per coarse bucket: fine sort by dst&255.
__global__ __launch_bounds__(512) void k_finesort(const unsigned* __restrict__ pairs,
                                                  const int* __restrict__ ch,
                                                  const int* __restrict__ cbase,
                                                  int* __restrict__ off,
                                                  float* __restrict__ dis,
                                                  int* __restrict__ ssrc, int n) {
  __shared__ int hist[256], lcur[256], wsum[4];
  __shared__ int sbuf[8192];
  int b = blockIdx.x;
  int node0 = b << 8;
  int nn = min(256, n - node0);
  int cnt = ch[b], base = cbase[b];
  int t = threadIdx.x;
  if (t < 256) hist[t] = 0;
  __syncthreads();
  for (int e = t; e < cnt; e += 512)
    atomicAdd(&hist[pairs[base + e] & 255u], 1);
  __syncthreads();
  if (t < 256) {
    int c = hist[t];
    int lane = t & 63, wv = t >> 6;
    int inc = c;
#pragma unroll
    for (int d = 1; d < 64; d <<= 1) {
      int u = __shfl_up(inc, d);
      if (lane >= d) inc += u;
    }
    if (lane == 63) wsum[wv] = inc;
    __syncthreads();
    int pre = 0;
    for (int w = 0; w < wv; ++w) pre += wsum[w];
    int exc = pre + inc - c;
    if (t < nn) {
      off[node0 + t] = base + exc;
      dis[node0 + t] = rsqrtf((float)(c + 1));
    }
    lcur[t] = exc;
  } else {
    __syncthreads();
  }
  __syncthreads();
  bool inlds = (cnt <= 8192);
  for (int e = t; e < cnt; e += 512) {
    unsigned p = pairs[base + e];
    int slot = atomicAdd(&lcur[p & 255u], 1);
    int sv = (int)(p >> 8);
    if (inlds) sbuf[slot] = sv;
    else       ssrc[base + slot] = sv;
  }
  __syncthreads();
  if (inlds)
    for (int e = t; e < cnt; e += 512) ssrc[base + e] = sbuf[e];
}

// ---------------- layer-1 tiled GEMM ----------------

__device__ __forceinline__ int swz(int r, int q) {
  return r * 16 + (q ^ ((r >> 3) & 7));
}

// h1b[n,64 bf16] = bf16( dis ⊙ (X[n,64] @ W[64,64]) ).  128 thr, 8x8/thread.
__global__ __launch_bounds__(128) void k_gemm64t(const float* __restrict__ X,
                                                 const float* __restrict__ W,
                                                 const float* __restrict__ dis,
                                                 unsigned* __restrict__ Hb, int n) {
  __shared__ float4 Xl[128 * 16];
  __shared__ float4 Wl[64 * 16];
  int t = threadIdx.x;
  int row0 = blockIdx.x * 128;
#pragma unroll
  for (int j = 0; j < 8; ++j) Wl[t + j * 128] = ((const float4*)W)[t + j * 128];
#pragma unroll
  for (int j = 0; j < 16; ++j) {
    int v = t + j * 128;
    int r = v >> 4, q = v & 15;
    int gr = row0 + r;
    float4 val = (gr < n) ? ((const float4*)X)[(size_t)gr * 16 + q]
                          : make_float4(0.f, 0.f, 0.f, 0.f);
    Xl[swz(r, q)] = val;
  }
  __syncthreads();
  int tx = t & 7, ty = t >> 3;
  float acc[8][8];
#pragma unroll
  for (int i = 0; i < 8; ++i)
#pragma unroll
    for (int j = 0; j < 8; ++j) acc[i][j] = 0.f;
  int tysw = ty & 7;
  for (int kq = 0; kq < 16; ++kq) {
    float x_[8][4];
#pragma unroll
    for (int i = 0; i < 8; ++i) {
      float4 v = Xl[(ty * 8 + i) * 16 + (kq ^ tysw)];
      x_[i][0] = v.x; x_[i][1] = v.y; x_[i][2] = v.z; x_[i][3] = v.w;
    }
#pragma unroll
    for (int kk = 0; kk < 4; ++kk) {
      int k = kq * 4 + kk;
      float4 w0 = Wl[k * 16 + tx * 2];
      float4 w1 = Wl[k * 16 + tx * 2 + 1];
      float w_[8] = {w0.x, w0.y, w0.z, w0.w, w1.x, w1.y, w1.z, w1.w};
#pragma unroll
      for (int i = 0; i < 8; ++i)
#pragma unroll
        for (int j = 0; j < 8; ++j)
          acc[i][j] = fmaf(x_[i][kk], w_[j], acc[i][j]);
    }
  }
#pragma unroll
  for (int i = 0; i < 8; ++i) {
    int r = row0 + ty * 8 + i;
    if (r < n) {
      float d = dis[r];
      uint4 o;
      o.x = bf16pair(acc[i][0] * d, acc[i][1] * d);
      o.y = bf16pair(acc[i][2] * d, acc[i][3] * d);
      o.z = bf16pair(acc[i][4] * d, acc[i][5] * d);
      o.w = bf16pair(acc[i][6] * d, acc[i][7] * d);
      ((uint4*)Hb)[(size_t)r * 8 + tx] = o;
    }
  }
}

// ---------------- fused gather + in-wave 64x32 GEMM (layer 2) ----------------
// One wave per node; lane = (q = lane&15 -> uint2 column, g = lane>>4 -> edge
// group). After the g-reduction every lane holds p-partials for its q.
// Then: per-lane 4x8 W2 slice in registers, partial products, q-reduction via
// shfl_xor(1,2,4,8); lanes q<4 of each g write 8 bf16 outputs.
__global__ __launch_bounds__(256) void k_gathergemm(const int* __restrict__ off,
                                                    const int* __restrict__ ssrc,
                                                    const float* __restrict__ dis,
                                                    const uint2* __restrict__ Hb2,
                                                    const float* __restrict__ b1,
                                                    const float* __restrict__ W2,
                                                    unsigned* __restrict__ H2b, int n) {
  int lane = threadIdx.x & 63;
  int q = lane & 15, g = lane >> 4;  // g = 0..3
  // Register-resident W2 slice: rows 4q..4q+3, cols 8g..8g+7 (32 floats).
  float w_[4][8];
#pragma unroll
  for (int m = 0; m < 4; ++m) {
    const float4* wr = (const float4*)(W2 + (4 * q + m) * 32 + 8 * g);
    float4 a = wr[0], b = wr[1];
    w_[m][0] = a.x; w_[m][1] = a.y; w_[m][2] = a.z; w_[m][3] = a.w;
    w_[m][4] = b.x; w_[m][5] = b.y; w_[m][6] = b.z; w_[m][7] = b.w;
  }
  int i = blockIdx.x * 4 + (threadIdx.x >> 6);
  if (i >= n) return;
  int beg = off[i], end = off[i + 1];
  float s0 = 0.f, s1 = 0.f, s2 = 0.f, s3 = 0.f;
  if (g == 0) {  // self-loop once
    uint2 v = Hb2[(size_t)i * 16 + q];
    s0 = bf_lo(v.x); s1 = bf_hi(v.x); s2 = bf_lo(v.y); s3 = bf_hi(v.y);
  }
  int e = beg + g;
  for (; e + 4 < end; e += 8) {
    uint2 v0 = Hb2[(size_t)ssrc[e]     * 16 + q];
    uint2 v1 = Hb2[(size_t)ssrc[e + 4] * 16 + q];
    s0 += bf_lo(v0.x) + bf_lo(v1.x);
    s1 += bf_hi(v0.x) + bf_hi(v1.x);
    s2 += bf_lo(v0.y) + bf_lo(v1.y);
    s3 += bf_hi(v0.y) + bf_hi(v1.y);
  }
  for (; e < end; e += 4) {
    uint2 v = Hb2[(size_t)ssrc[e] * 16 + q];
    s0 += bf_lo(v.x); s1 += bf_hi(v.x); s2 += bf_lo(v.y); s3 += bf_hi(v.y);
  }
  // reduce over edge groups (lane bits 4,5): every lane now holds sums for q
  s0 += __shfl_xor(s0, 16); s1 += __shfl_xor(s1, 16);
  s2 += __shfl_xor(s2, 16); s3 += __shfl_xor(s3, 16);
  s0 += __shfl_xor(s0, 32); s1 += __shfl_xor(s1, 32);
  s2 += __shfl_xor(s2, 32); s3 += __shfl_xor(s3, 32);
  float di = dis[i];
  float4 bb = ((const float4*)b1)[q];
  float p0 = fmaxf(fmaf(di, s0, bb.x), 0.f);
  float p1 = fmaxf(fmaf(di, s1, bb.y), 0.f);
  float p2 = fmaxf(fmaf(di, s2, bb.z), 0.f);
  float p3 = fmaxf(fmaf(di, s3, bb.w), 0.f);
  // partial products for outputs 8g..8g+7
  float acc[8];
#pragma unroll
  for (int j = 0; j < 8; ++j)
    acc[j] = fmaf(p0, w_[0][j], fmaf(p1, w_[1][j], fmaf(p2, w_[2][j], p3 * w_[3][j])));
  // reduce over q (lane bits 0..3)
#pragma unroll
  for (int d = 1; d < 16; d <<= 1) {
#pragma unroll
    for (int j = 0; j < 8; ++j) acc[j] += __shfl_xor(acc[j], d);
  }
  if (q < 4) {
    unsigned o = bf16pair(di * acc[2 * q], di * acc[2 * q + 1]);
    H2b[(size_t)i * 16 + g * 4 + q] = o;
  }
}

// ---------------- final gather (layer-2 aggregation) ----------------

// One wave per node; lane&7 = uint2 column (4 features), lane>>3 = edge group.
__global__ __launch_bounds__(256) void k_gather32v(const int* __restrict__ off,
                                                   const int* __restrict__ ssrc,
                                                   const float* __restrict__ dis,
                                                   const uint2* __restrict__ Hb2,
                                                   const float* __restrict__ b2,
                                                   float* __restrict__ out, int n) {
  int lane = threadIdx.x & 63;
  int q = lane & 7, g = lane >> 3;  // g = 0..7
  int i = blockIdx.x * 4 + (threadIdx.x >> 6);
  if (i >= n) return;
  int beg = off[i], end = off[i + 1];
  float s0 = 0.f, s1 = 0.f, s2 = 0.f, s3 = 0.f;
  if (g == 0) {  // self-loop once
    uint2 v = Hb2[(size_t)i * 8 + q];
    s0 = bf_lo(v.x); s1 = bf_hi(v.x); s2 = bf_lo(v.y); s3 = bf_hi(v.y);
  }
  int e = beg + g;
  for (; e + 8 < end; e += 16) {
    uint2 v0 = Hb2[(size_t)ssrc[e]     * 8 + q];
    uint2 v1 = Hb2[(size_t)ssrc[e + 8] * 8 + q];
    s0 += bf_lo(v0.x) + bf_lo(v1.x);
    s1 += bf_hi(v0.x) + bf_hi(v1.x);
    s2 += bf_lo(v0.y) + bf_lo(v1.y);
    s3 += bf_hi(v0.y) + bf_hi(v1.y);
  }
  for (; e < end; e += 8) {
    uint2 v = Hb2[(size_t)ssrc[e] * 8 + q];
    s0 += bf_lo(v.x); s1 += bf_hi(v.x); s2 += bf_lo(v.y); s3 += bf_hi(v.y);
  }
  s0 += __shfl_xor(s0, 8);  s1 += __shfl_xor(s1, 8);
  s2 += __shfl_xor(s2, 8);  s3 += __shfl_xor(s3, 8);
  s0 += __shfl_xor(s0, 16); s1 += __shfl_xor(s1, 16);
  s2 += __shfl_xor(s2, 16); s3 += __shfl_xor(s3, 16);
  s0 += __shfl_xor(s0, 32); s1 += __shfl_xor(s1, 32);
  s2 += __shfl_xor(s2, 32); s3 += __shfl_xor(s3, 32);
  if (lane < 8) {
    float di = dis[i];
    float4 b = ((const float4*)b2)[q];
    float4 o;
    o.x = fmaxf(fmaf(di, s0, b.x), 0.f);
    o.y = fmaxf(fmaf(di, s1, b.y), 0.f);
    o.z = fmaxf(fmaf(di, s2, b.z), 0.f);
    o.w = fmaxf(fmaf(di, s3, b.w), 0.f);
    ((float4*)out)[(size_t)i * 8 + q] = o;
  }
}

extern "C" void kernel_launch(void* const* d_in, const int* in_sizes, int n_in,
                              void* d_out, int out_size, void* d_ws, size_t ws_size,
                              hipStream_t stream) {
  const float* x  = (const float*)d_in[0];
  const int*   ei = (const int*)d_in[1];
  const float* W1 = (const float*)d_in[2];
  const float* b1 = (const float*)d_in[3];
  const float* W2 = (const float*)d_in[4];
  const float* b2 = (const float*)d_in[5];
  float* out = (float*)d_out;

  const int n = in_sizes[0] / 64;
  const int E = in_sizes[1] / 2;
  const int* src = ei;
  const int* dst = ei + E;
  const int NB = (n + 255) >> 8;

  // 16B-aligned workspace carve-out.
  char* wp = (char*)d_ws;
  auto alloc = [&](size_t bytes) {
    char* p = wp;
    wp += (bytes + 15) & ~(size_t)15;
    return (void*)p;
  };
  unsigned* pairs = (unsigned*)alloc((size_t)E * 4);
  int*      ch    = (int*)alloc(NBMAX * 4);
  int*      cbase = (int*)alloc(NBMAX * 4);
  int*      gcur  = (int*)alloc(NBMAX * 4);
  int*      off   = (int*)alloc(((size_t)n + 1) * 4);
  float*    dis   = (float*)alloc((size_t)n * 4);
  int*      ssrc  = (int*)alloc((size_t)E * 4);
  unsigned* h1b   = (unsigned*)alloc((size_t)n * 64 * 2);  // bf16 [n][64]
  unsigned* h2b   = (unsigned*)alloc((size_t)n * 32 * 2);  // bf16 [n][32]

  auto cdiv = [](long long a, long long b) { return (unsigned)((a + b - 1) / b); };
  dim3 B(256);

  hipMemsetAsync(ch, 0, (size_t)NBMAX * 4, stream);
  k_coarsehist<<<512, B, 0, stream>>>(dst, ch, E, NB);
  k_scanb     <<<1, 512, 0, stream>>>(ch, cbase, gcur, off, NB, n, E);
  k_binpairs  <<<cdiv(E, BIN_TILE), B, 0, stream>>>(src, dst, gcur, pairs, E, NB);
  k_finesort  <<<NB, 512, 0, stream>>>(pairs, ch, cbase, off, dis, ssrc, n);

  k_gemm64t   <<<cdiv(n, 128), 128, 0, stream>>>(x, W1, dis, h1b, n);
  k_gathergemm<<<cdiv(n, 4), B, 0, stream>>>(off, ssrc, dis, (const uint2*)h1b, b1, W2, h2b, n);
  k_gather32v <<<cdiv(n, 4), B, 0, stream>>>(off, ssrc, dis, (const uint2*)h2b, b2, out, n);
}

// Round 11
// 224.068 us; speedup vs baseline: 1.1696x; 1.1696x over previous
//
#include <hip/hip_runtime.h>

// 2-layer GCN on MI355X — gather formulation, two-level counting sort,
// dis-prescaled bf16 features, tiled GEMMs, feature-split layer-1 gather
// (two 6.4MB half arrays -> per-XCD-L2-friendly random access).
//
// out = relu(Ahat @ relu(Ahat @ (x@W1) + b1) @ W2 + b2),
// Ahat = D^-1/2 (A+I) D^-1/2.
//
// Pipeline:
//  1. counting sort (packed uint pairs) -> off[], dis[], ssrc[]
//  2. k_gemm64t   : h1lo/h1hi = bf16( dis ⊙ (x @ W1) )   [two [n][32] halves]
//  3. k_gather64h : (x2, one per half) p1[:, half] =
//                   relu(dis[i]*(Σ h1half[src] + h1half[i]) + b1half)  (f32)
//  4. k_gemm32t   : h2b = bf16( dis ⊙ (p1 @ W2) )        [tiled 8x4/thread]
//  5. k_gather32v : out = relu(dis[i]*(Σ h2b[src] + h2b[i]) + b2)  (f32)

#define NBMAX 512  // coarse buckets (dst>>8); requires n < 2^17

// ---- bf16 pack/unpack (round-to-nearest-even) ----
__device__ __forceinline__ unsigned bf16pair(float a, float b) {
  unsigned ua = __float_as_uint(a), ub = __float_as_uint(b);
  ua = (ua + 0x7fffu + ((ua >> 16) & 1u)) >> 16;
  ub = (ub + 0x7fffu + ((ub >> 16) & 1u)) >> 16;
  return ua | (ub << 16);
}
__device__ __forceinline__ float bf_lo(unsigned v) { return __uint_as_float(v << 16); }
__device__ __forceinline__ float bf_hi(unsigned v) { return __uint_as_float(v & 0xffff0000u); }

// ---------------- sort pipeline ----------------

__global__ __launch_bounds__(256) void k_coarsehist(const int* __restrict__ dst,
                                                    int* __restrict__ ch,
                                                    int E, int NB) {
  __shared__ int lh[NBMAX];
  int t = threadIdx.x;
  lh[t] = 0; lh[t + 256] = 0;
  __syncthreads();
  for (int e = blockIdx.x * 256 + t; e < E; e += gridDim.x * 256)
    atomicAdd(&lh[dst[e] >> 8], 1);
  __syncthreads();
  for (int b = t; b < NB; b += 256) {
    int c = lh[b];
    if (c) atomicAdd(&ch[b], c);
  }
}

__global__ __launch_bounds__(512) void k_scanb(const int* __restrict__ ch,
                                               int* __restrict__ cbase,
                                               int* __restrict__ gcur,
                                               int* __restrict__ off,
                                               int NB, int n, int E) {
  __shared__ int lds[512];
  int t = threadIdx.x;
  int v = (t < NB) ? ch[t] : 0;
  lds[t] = v;
  __syncthreads();
  for (int d = 1; d < 512; d <<= 1) {
    int u = (t >= d) ? lds[t - d] : 0;
    __syncthreads();
    lds[t] += u;
    __syncthreads();
  }
  if (t < NB) {
    int exc = lds[t] - v;
    cbase[t] = exc;
    gcur[t]  = exc;
  }
  if (t == 0) off[n] = E;
}

// Tile-phased binning: packed (src<<8 | dst&255) runs per coarse bucket.
#define BIN_TILE 4096
__global__ __launch_bounds__(256) void k_binpairs(const int* __restrict__ src,
                                                  const int* __restrict__ dst,
                                                  int* __restrict__ gcur,
                                                  unsigned* __restrict__ pairs,
                                                  int E, int NB) {
  __shared__ int lcnt[NBMAX], gbase[NBMAX];
  int t = threadIdx.x;
  int tile0 = blockIdx.x * BIN_TILE;
  lcnt[t] = 0; lcnt[t + 256] = 0;
  __syncthreads();
#pragma unroll
  for (int j = 0; j < BIN_TILE / 256; ++j) {
    int e = tile0 + j * 256 + t;
    if (e < E) atomicAdd(&lcnt[dst[e] >> 8], 1);
  }
  __syncthreads();
  for (int b = t; b < NB; b += 256) {
    int c = lcnt[b];
    if (c) gbase[b] = atomicAdd(&gcur[b], c);
    lcnt[b] = 0;
  }
  __syncthreads();
#pragma unroll
  for (int j = 0; j < BIN_TILE / 256; ++j) {
    int e = tile0 + j * 256 + t;
    if (e < E) {
      int dv = dst[e];
      int b  = dv >> 8;
      int slot = atomicAdd(&lcnt[b], 1);
      pairs[gbase[b] + slot] = ((unsigned)src[e] << 8) | (unsigned)(dv & 255);
    }
  }
}

// One block (512 thr) per coarse bucket: fine sort by dst&255.
__global__ __launch_bounds__(512) void k_finesort(const unsigned* __restrict__ pairs,
                                                  const int* __restrict__ ch,
                                                  const int* __restrict__ cbase,
                                                  int* __restrict__ off,
                                                  float* __restrict__ dis,
                                                  int* __restrict__ ssrc, int n) {
  __shared__ int hist[256], lcur[256], wsum[4];
  __shared__ int sbuf[8192];
  int b = blockIdx.x;
  int node0 = b << 8;
  int nn = min(256, n - node0);
  int cnt = ch[b], base = cbase[b];
  int t = threadIdx.x;
  if (t < 256) hist[t] = 0;
  __syncthreads();
  for (int e = t; e < cnt; e += 512)
    atomicAdd(&hist[pairs[base + e] & 255u], 1);
  __syncthreads();
  int c = 0, inc = 0;
  if (t < 256) {
    c = hist[t];
    int lane = t & 63;
    inc = c;
#pragma unroll
    for (int d = 1; d < 64; d <<= 1) {
      int u = __shfl_up(inc, d);
      if (lane >= d) inc += u;
    }
    if (lane == 63) wsum[t >> 6] = inc;
  }
  __syncthreads();
  if (t < 256) {
    int wv = t >> 6;
    int pre = 0;
    for (int w = 0; w < wv; ++w) pre += wsum[w];
    int exc = pre + inc - c;
    if (t < nn) {
      off[node0 + t] = base + exc;
      dis[node0 + t] = rsqrtf((float)(c + 1));
    }
    lcur[t] = exc;
  }
  __syncthreads();
  bool inlds = (cnt <= 8192);
  for (int e = t; e < cnt; e += 512) {
    unsigned p = pairs[base + e];
    int slot = atomicAdd(&lcur[p & 255u], 1);
    int sv = (int)(p >> 8);
    if (inlds) sbuf[slot] = sv;
    else       ssrc[base + slot] = sv;
  }
  __syncthreads();
  if (inlds)
    for (int e = t; e < cnt; e += 512) ssrc[base + e] = sbuf[e];
}

// ---------------- layer-1 tiled GEMM ----------------

__device__ __forceinline__ int swz(int r, int q) {
  return r * 16 + (q ^ ((r >> 3) & 7));
}

// h1 halves: Hlo[n][32 bf16] (feats 0..31), Hhi[n][32 bf16] (feats 32..63),
// both = bf16( dis ⊙ (X @ W1) ).  128 thr, 8x8/thread.
__global__ __launch_bounds__(128) void k_gemm64t(const float* __restrict__ X,
                                                 const float* __restrict__ W,
                                                 const float* __restrict__ dis,
                                                 unsigned* __restrict__ Hlo,
                                                 unsigned* __restrict__ Hhi, int n) {
  __shared__ float4 Xl[128 * 16];
  __shared__ float4 Wl[64 * 16];
  int t = threadIdx.x;
  int row0 = blockIdx.x * 128;
#pragma unroll
  for (int j = 0; j < 8; ++j) Wl[t + j * 128] = ((const float4*)W)[t + j * 128];
#pragma unroll
  for (int j = 0; j < 16; ++j) {
    int v = t + j * 128;
    int r = v >> 4, q = v & 15;
    int gr = row0 + r;
    float4 val = (gr < n) ? ((const float4*)X)[(size_t)gr * 16 + q]
                          : make_float4(0.f, 0.f, 0.f, 0.f);
    Xl[swz(r, q)] = val;
  }
  __syncthreads();
  int tx = t & 7, ty = t >> 3;
  float acc[8][8];
#pragma unroll
  for (int i = 0; i < 8; ++i)
#pragma unroll
    for (int j = 0; j < 8; ++j) acc[i][j] = 0.f;
  int tysw = ty & 7;
  for (int kq = 0; kq < 16; ++kq) {
    float x_[8][4];
#pragma unroll
    for (int i = 0; i < 8; ++i) {
      float4 v = Xl[(ty * 8 + i) * 16 + (kq ^ tysw)];
      x_[i][0] = v.x; x_[i][1] = v.y; x_[i][2] = v.z; x_[i][3] = v.w;
    }
#pragma unroll
    for (int kk = 0; kk < 4; ++kk) {
      int k = kq * 4 + kk;
      float4 w0 = Wl[k * 16 + tx * 2];
      float4 w1 = Wl[k * 16 + tx * 2 + 1];
      float w_[8] = {w0.x, w0.y, w0.z, w0.w, w1.x, w1.y, w1.z, w1.w};
#pragma unroll
      for (int i = 0; i < 8; ++i)
#pragma unroll
        for (int j = 0; j < 8; ++j)
          acc[i][j] = fmaf(x_[i][kk], w_[j], acc[i][j]);
    }
  }
  unsigned* Hb = (tx < 4) ? Hlo : Hhi;
  int txx = tx & 3;
#pragma unroll
  for (int i = 0; i < 8; ++i) {
    int r = row0 + ty * 8 + i;
    if (r < n) {
      float d = dis[r];
      uint4 o;
      o.x = bf16pair(acc[i][0] * d, acc[i][1] * d);
      o.y = bf16pair(acc[i][2] * d, acc[i][3] * d);
      o.z = bf16pair(acc[i][4] * d, acc[i][5] * d);
      o.w = bf16pair(acc[i][6] * d, acc[i][7] * d);
      ((uint4*)Hb)[(size_t)r * 4 + txx] = o;
    }
  }
}

// ---------------- layer-1 gather, one feature-half per launch ----------------
// One wave per node; q = lane&7 -> uint2 column (4 feats of the half),
// g = lane>>3 -> edge group (8 groups), unroll x2.
// P4 is (float4*)p1 pre-offset by 8*half; b1h = b1 + 32*half.
__global__ __launch_bounds__(256) void k_gather64h(const int* __restrict__ off,
                                                   const int* __restrict__ ssrc,
                                                   const float* __restrict__ dis,
                                                   const uint2* __restrict__ Hb2,
                                                   const float* __restrict__ b1h,
                                                   float4* __restrict__ P4, int n) {
  int lane = threadIdx.x & 63;
  int q = lane & 7, g = lane >> 3;  // g = 0..7
  int i = blockIdx.x * 4 + (threadIdx.x >> 6);
  if (i >= n) return;
  int beg = off[i], end = off[i + 1];
  float s0 = 0.f, s1 = 0.f, s2 = 0.f, s3 = 0.f;
  if (g == 0) {  // self-loop once
    uint2 v = Hb2[(size_t)i * 8 + q];
    s0 = bf_lo(v.x); s1 = bf_hi(v.x); s2 = bf_lo(v.y); s3 = bf_hi(v.y);
  }
  int e = beg + g;
  for (; e + 8 < end; e += 16) {
    uint2 v0 = Hb2[(size_t)ssrc[e]     * 8 + q];
    uint2 v1 = Hb2[(size_t)ssrc[e + 8] * 8 + q];
    s0 += bf_lo(v0.x) + bf_lo(v1.x);
    s1 += bf_hi(v0.x) + bf_hi(v1.x);
    s2 += bf_lo(v0.y) + bf_lo(v1.y);
    s3 += bf_hi(v0.y) + bf_hi(v1.y);
  }
  for (; e < end; e += 8) {
    uint2 v = Hb2[(size_t)ssrc[e] * 8 + q];
    s0 += bf_lo(v.x); s1 += bf_hi(v.x); s2 += bf_lo(v.y); s3 += bf_hi(v.y);
  }
  s0 += __shfl_xor(s0, 8);  s1 += __shfl_xor(s1, 8);
  s2 += __shfl_xor(s2, 8);  s3 += __shfl_xor(s3, 8);
  s0 += __shfl_xor(s0, 16); s1 += __shfl_xor(s1, 16);
  s2 += __shfl_xor(s2, 16); s3 += __shfl_xor(s3, 16);
  s0 += __shfl_xor(s0, 32); s1 += __shfl_xor(s1, 32);
  s2 += __shfl_xor(s2, 32); s3 += __shfl_xor(s3, 32);
  if (lane < 8) {
    float di = dis[i];
    float4 b = ((const float4*)b1h)[q];
    float4 o;
    o.x = fmaxf(fmaf(di, s0, b.x), 0.f);
    o.y = fmaxf(fmaf(di, s1, b.y), 0.f);
    o.z = fmaxf(fmaf(di, s2, b.z), 0.f);
    o.w = fmaxf(fmaf(di, s3, b.w), 0.f);
    P4[(size_t)i * 16 + q] = o;
  }
}

// ---------------- layer-2 tiled GEMM (f32 in, bf16 out) ----------------

// h2b[n,32 bf16] = bf16( dis ⊙ (P[n,64] @ W2[64,32]) ).  128 thr, 8x4/thread.
__global__ __launch_bounds__(128) void k_gemm32t(const float* __restrict__ P,
                                                 const float* __restrict__ W2,
                                                 const float* __restrict__ dis,
                                                 unsigned* __restrict__ Hb, int n) {
  __shared__ float4 Pl[128 * 16];
  __shared__ float4 Wl[64 * 8];
  int t = threadIdx.x;
  int row0 = blockIdx.x * 128;
#pragma unroll
  for (int j = 0; j < 4; ++j) Wl[t + j * 128] = ((const float4*)W2)[t + j * 128];
#pragma unroll
  for (int j = 0; j < 16; ++j) {
    int v = t + j * 128;
    int r = v >> 4, q = v & 15;
    int gr = row0 + r;
    float4 val = (gr < n) ? ((const float4*)P)[(size_t)gr * 16 + q]
                          : make_float4(0.f, 0.f, 0.f, 0.f);
    Pl[swz(r, q)] = val;
  }
  __syncthreads();
  int tx = t & 7, ty = t >> 3;
  float acc[8][4];
#pragma unroll
  for (int i = 0; i < 8; ++i)
#pragma unroll
    for (int j = 0; j < 4; ++j) acc[i][j] = 0.f;
  int tysw = ty & 7;
  for (int kq = 0; kq < 16; ++kq) {
    float x_[8][4];
#pragma unroll
    for (int i = 0; i < 8; ++i) {
      float4 v = Pl[(ty * 8 + i) * 16 + (kq ^ tysw)];
      x_[i][0] = v.x; x_[i][1] = v.y; x_[i][2] = v.z; x_[i][3] = v.w;
    }
#pragma unroll
    for (int kk = 0; kk < 4; ++kk) {
      int k = kq * 4 + kk;
      float4 w = Wl[k * 8 + tx];
      float w_[4] = {w.x, w.y, w.z, w.w};
#pragma unroll
      for (int i = 0; i < 8; ++i)
#pragma unroll
        for (int j = 0; j < 4; ++j)
          acc[i][j] = fmaf(x_[i][kk], w_[j], acc[i][j]);
    }
  }
#pragma unroll
  for (int i = 0; i < 8; ++i) {
    int r = row0 + ty * 8 + i;
    if (r < n) {
      float d = dis[r];
      uint2 o;
      o.x = bf16pair(acc[i][0] * d, acc[i][1] * d);
      o.y = bf16pair(acc[i][2] * d, acc[i][3] * d);
      ((uint2*)Hb)[(size_t)r * 8 + tx] = o;
    }
  }
}

// ---------------- final gather (layer-2 aggregation) ----------------

// One wave per node; lane&7 = uint2 column (4 features), lane>>3 = edge group.
__global__ __launch_bounds__(256) void k_gather32v(const int* __restrict__ off,
                                                   const int* __restrict__ ssrc,
                                                   const float* __restrict__ dis,
                                                   const uint2* __restrict__ Hb2,
                                                   const float* __restrict__ b2,
                                                   float* __restrict__ out, int n) {
  int lane = threadIdx.x & 63;
  int q = lane & 7, g = lane >> 3;  // g = 0..7
  int i = blockIdx.x * 4 + (threadIdx.x >> 6);
  if (i >= n) return;
  int beg = off[i], end = off[i + 1];
  float s0 = 0.f, s1 = 0.f, s2 = 0.f, s3 = 0.f;
  if (g == 0) {  // self-loop once
    uint2 v = Hb2[(size_t)i * 8 + q];
    s0 = bf_lo(v.x); s1 = bf_hi(v.x); s2 = bf_lo(v.y); s3 = bf_hi(v.y);
  }
  int e = beg + g;
  for (; e + 8 < end; e += 16) {
    uint2 v0 = Hb2[(size_t)ssrc[e]     * 8 + q];
    uint2 v1 = Hb2[(size_t)ssrc[e + 8] * 8 + q];
    s0 += bf_lo(v0.x) + bf_lo(v1.x);
    s1 += bf_hi(v0.x) + bf_hi(v1.x);
    s2 += bf_lo(v0.y) + bf_lo(v1.y);
    s3 += bf_hi(v0.y) + bf_hi(v1.y);
  }
  for (; e < end; e += 8) {
    uint2 v = Hb2[(size_t)ssrc[e] * 8 + q];
    s0 += bf_lo(v.x); s1 += bf_hi(v.x); s2 += bf_lo(v.y); s3 += bf_hi(v.y);
  }
  s0 += __shfl_xor(s0, 8);  s1 += __shfl_xor(s1, 8);
  s2 += __shfl_xor(s2, 8);  s3 += __shfl_xor(s3, 8);
  s0 += __shfl_xor(s0, 16); s1 += __shfl_xor(s1, 16);
  s2 += __shfl_xor(s2, 16); s3 += __shfl_xor(s3, 16);
  s0 += __shfl_xor(s0, 32); s1 += __shfl_xor(s1, 32);
  s2 += __shfl_xor(s2, 32); s3 += __shfl_xor(s3, 32);
  if (lane < 8) {
    float di = dis[i];
    float4 b = ((const float4*)b2)[q];
    float4 o;
    o.x = fmaxf(fmaf(di, s0, b.x), 0.f);
    o.y = fmaxf(fmaf(di, s1, b.y), 0.f);
    o.z = fmaxf(fmaf(di, s2, b.z), 0.f);
    o.w = fmaxf(fmaf(di, s3, b.w), 0.f);
    ((float4*)out)[(size_t)i * 8 + q] = o;
  }
}

extern "C" void kernel_launch(void* const* d_in, const int* in_sizes, int n_in,
                              void* d_out, int out_size, void* d_ws, size_t ws_size,
                              hipStream_t stream) {
  const float* x  = (const float*)d_in[0];
  const int*   ei = (const int*)d_in[1];
  const float* W1 = (const float*)d_in[2];
  const float* b1 = (const float*)d_in[3];
  const float* W2 = (const float*)d_in[4];
  const float* b2 = (const float*)d_in[5];
  float* out = (float*)d_out;

  const int n = in_sizes[0] / 64;
  const int E = in_sizes[1] / 2;
  const int* src = ei;
  const int* dst = ei + E;
  const int NB = (n + 255) >> 8;

  // 16B-aligned workspace carve-out.
  char* wp = (char*)d_ws;
  auto alloc = [&](size_t bytes) {
    char* p = wp;
    wp += (bytes + 15) & ~(size_t)15;
    return (void*)p;
  };
  unsigned* pairs = (unsigned*)alloc((size_t)E * 4);
  int*      ch    = (int*)alloc(NBMAX * 4);
  int*      cbase = (int*)alloc(NBMAX * 4);
  int*      gcur  = (int*)alloc(NBMAX * 4);
  int*      off   = (int*)alloc(((size_t)n + 1) * 4);
  float*    dis   = (float*)alloc((size_t)n * 4);
  int*      ssrc  = (int*)alloc((size_t)E * 4);
  unsigned* h1lo  = (unsigned*)alloc((size_t)n * 32 * 2);  // bf16 [n][32] feats 0-31
  unsigned* h1hi  = (unsigned*)alloc((size_t)n * 32 * 2);  // bf16 [n][32] feats 32-63
  float*    p1    = (float*)alloc((size_t)n * 64 * 4);     // f32  [n][64]
  unsigned* h2b   = (unsigned*)alloc((size_t)n * 32 * 2);  // bf16 [n][32]

  auto cdiv = [](long long a, long long b) { return (unsigned)((a + b - 1) / b); };
  dim3 B(256);

  hipMemsetAsync(ch, 0, (size_t)NBMAX * 4, stream);
  k_coarsehist<<<512, B, 0, stream>>>(dst, ch, E, NB);
  k_scanb     <<<1, 512, 0, stream>>>(ch, cbase, gcur, off, NB, n, E);
  k_binpairs  <<<cdiv(E, BIN_TILE), B, 0, stream>>>(src, dst, gcur, pairs, E, NB);
  k_finesort  <<<NB, 512, 0, stream>>>(pairs, ch, cbase, off, dis, ssrc, n);

  k_gemm64t   <<<cdiv(n, 128), 128, 0, stream>>>(x, W1, dis, h1lo, h1hi, n);
  k_gather64h <<<cdiv(n, 4), B, 0, stream>>>(off, ssrc, dis, (const uint2*)h1lo,
                                             b1,      (float4*)p1,     n);
  k_gather64h <<<cdiv(n, 4), B, 0, stream>>>(off, ssrc, dis, (const uint2*)h1hi,
                                             b1 + 32, (float4*)p1 + 8, n);
  k_gemm32t   <<<cdiv(n, 128), 128, 0, stream>>>(p1, W2, dis, h2b, n);
  k_gather32v <<<cdiv(n, 4), B, 0, stream>>>(off, ssrc, dis, (const uint2*)h2b, b2, out, n);
}

// Round 13
// 216.030 us; speedup vs baseline: 1.2131x; 1.0372x over previous
//
#include <hip/hip_runtime.h>

// 2-layer GCN on MI355X — gather formulation, two-level counting sort,
// dis-prescaled bf16 features, tiled GEMMs, deep gathers with
// non-temporal hints on streaming buffers (keep L2 for the random rows).
//
// out = relu(Ahat @ relu(Ahat @ (x@W1) + b1) @ W2 + b2),
// Ahat = D^-1/2 (A+I) D^-1/2.
//
// Pipeline:
//  1. counting sort (packed uint pairs) -> off[], dis[], ssrc[]
//  2. k_gemm64t  : h1b = bf16( dis ⊙ (x @ W1) )         [tiled 8x8/thread]
//  3. k_gather64v: p1 = relu(dis[i]*(Σ h1b[src] + h1b[i]) + b1)   (f32, NT store)
//  4. k_gemm32t  : h2b = bf16( dis ⊙ (p1 @ W2) )        [tiled 8x4/thread]
//  5. k_gather32v: out = relu(dis[i]*(Σ h2b[src] + h2b[i]) + b2)  (NT store)

#define NBMAX 512  // coarse buckets (dst>>8); requires n < 2^17
#define BIN_TILE 4096

typedef float f32x4 __attribute__((ext_vector_type(4)));  // native vec for NT store

// ---- bf16 pack/unpack (round-to-nearest-even) ----
__device__ __forceinline__ unsigned bf16pair(float a, float b) {
  unsigned ua = __float_as_uint(a), ub = __float_as_uint(b);
  ua = (ua + 0x7fffu + ((ua >> 16) & 1u)) >> 16;
  ub = (ub + 0x7fffu + ((ub >> 16) & 1u)) >> 16;
  return ua | (ub << 16);
}
__device__ __forceinline__ float bf_lo(unsigned v) { return __uint_as_float(v << 16); }
__device__ __forceinline__ float bf_hi(unsigned v) { return __uint_as_float(v & 0xffff0000u); }

// ---------------- sort pipeline ----------------

__global__ __launch_bounds__(256) void k_coarsehist(const int* __restrict__ dst,
                                                    int* __restrict__ ch,
                                                    int E, int NB) {
  __shared__ int lh[NBMAX];
  int t = threadIdx.x;
  lh[t] = 0; lh[t + 256] = 0;
  __syncthreads();
  for (int e = blockIdx.x * 256 + t; e < E; e += gridDim.x * 256)
    atomicAdd(&lh[dst[e] >> 8], 1);
  __syncthreads();
  for (int b = t; b < NB; b += 256) {
    int c = lh[b];
    if (c) atomicAdd(&ch[b], c);
  }
}

__global__ __launch_bounds__(512) void k_scanb(const int* __restrict__ ch,
                                               int* __restrict__ cbase,
                                               int* __restrict__ gcur,
                                               int* __restrict__ off,
                                               int NB, int n, int E) {
  __shared__ int lds[512];
  int t = threadIdx.x;
  int v = (t < NB) ? ch[t] : 0;
  lds[t] = v;
  __syncthreads();
  for (int d = 1; d < 512; d <<= 1) {
    int u = (t >= d) ? lds[t - d] : 0;
    __syncthreads();
    lds[t] += u;
    __syncthreads();
  }
  if (t < NB) {
    int exc = lds[t] - v;
    cbase[t] = exc;
    gcur[t]  = exc;
  }
  if (t == 0) off[n] = E;
}

// Tile-phased binning: packed (src<<8 | dst&255) runs per coarse bucket.
__global__ __launch_bounds__(256) void k_binpairs(const int* __restrict__ src,
                                                  const int* __restrict__ dst,
                                                  int* __restrict__ gcur,
                                                  unsigned* __restrict__ pairs,
                                                  int E, int NB) {
  __shared__ int lcnt[NBMAX], gbase[NBMAX];
  int t = threadIdx.x;
  int tile0 = blockIdx.x * BIN_TILE;
  lcnt[t] = 0; lcnt[t + 256] = 0;
  __syncthreads();
#pragma unroll
  for (int j = 0; j < BIN_TILE / 256; ++j) {
    int e = tile0 + j * 256 + t;
    if (e < E) atomicAdd(&lcnt[dst[e] >> 8], 1);
  }
  __syncthreads();
  for (int b = t; b < NB; b += 256) {
    int c = lcnt[b];
    if (c) gbase[b] = atomicAdd(&gcur[b], c);
    lcnt[b] = 0;
  }
  __syncthreads();
#pragma unroll
  for (int j = 0; j < BIN_TILE / 256; ++j) {
    int e = tile0 + j * 256 + t;
    if (e < E) {
      int dv = dst[e];
      int b  = dv >> 8;
      int slot = atomicAdd(&lcnt[b], 1);
      pairs[gbase[b] + slot] = ((unsigned)src[e] << 8) | (unsigned)(dv & 255);
    }
  }
}

// One block (512 thr) per coarse bucket: fine sort by dst&255.
__global__ __launch_bounds__(512) void k_finesort(const unsigned* __restrict__ pairs,
                                                  const int* __restrict__ ch,
                                                  const int* __restrict__ cbase,
                                                  int* __restrict__ off,
                                                  float* __restrict__ dis,
                                                  int* __restrict__ ssrc, int n) {
  __shared__ int hist[256], lcur[256], wsum[4];
  __shared__ int sbuf[8192];
  int b = blockIdx.x;
  int node0 = b << 8;
  int nn = min(256, n - node0);
  int cnt = ch[b], base = cbase[b];
  int t = threadIdx.x;
  if (t < 256) hist[t] = 0;
  __syncthreads();
  for (int e = t; e < cnt; e += 512)
    atomicAdd(&hist[pairs[base + e] & 255u], 1);
  __syncthreads();
  int c = 0, inc = 0;
  if (t < 256) {
    c = hist[t];
    int lane = t & 63;
    inc = c;
#pragma unroll
    for (int d = 1; d < 64; d <<= 1) {
      int u = __shfl_up(inc, d);
      if (lane >= d) inc += u;
    }
    if (lane == 63) wsum[t >> 6] = inc;
  }
  __syncthreads();
  if (t < 256) {
    int wv = t >> 6;
    int pre = 0;
    for (int w = 0; w < wv; ++w) pre += wsum[w];
    int exc = pre + inc - c;
    if (t < nn) {
      off[node0 + t] = base + exc;
      dis[node0 + t] = rsqrtf((float)(c + 1));
    }
    lcur[t] = exc;
  }
  __syncthreads();
  bool inlds = (cnt <= 8192);
  for (int e = t; e < cnt; e += 512) {
    unsigned p = pairs[base + e];
    int slot = atomicAdd(&lcur[p & 255u], 1);
    int sv = (int)(p >> 8);
    if (inlds) sbuf[slot] = sv;
    else       ssrc[base + slot] = sv;
  }
  __syncthreads();
  if (inlds)
    for (int e = t; e < cnt; e += 512) ssrc[base + e] = sbuf[e];
}

// ---------------- tiled GEMMs ----------------

__device__ __forceinline__ int swz(int r, int q) {
  return r * 16 + (q ^ ((r >> 3) & 7));
}

// h1b[n,64 bf16] = bf16( dis ⊙ (X[n,64] @ W[64,64]) ).  128 thr, 8x8/thread.
__global__ __launch_bounds__(128) void k_gemm64t(const float* __restrict__ X,
                                                 const float* __restrict__ W,
                                                 const float* __restrict__ dis,
                                                 unsigned* __restrict__ Hb, int n) {
  __shared__ float4 Xl[128 * 16];
  __shared__ float4 Wl[64 * 16];
  int t = threadIdx.x;
  int row0 = blockIdx.x * 128;
#pragma unroll
  for (int j = 0; j < 8; ++j) Wl[t + j * 128] = ((const float4*)W)[t + j * 128];
#pragma unroll
  for (int j = 0; j < 16; ++j) {
    int v = t + j * 128;
    int r = v >> 4, q = v & 15;
    int gr = row0 + r;
    float4 val = (gr < n) ? ((const float4*)X)[(size_t)gr * 16 + q]
                          : make_float4(0.f, 0.f, 0.f, 0.f);
    Xl[swz(r, q)] = val;
  }
  __syncthreads();
  int tx = t & 7, ty = t >> 3;
  float acc[8][8];
#pragma unroll
  for (int i = 0; i < 8; ++i)
#pragma unroll
    for (int j = 0; j < 8; ++j) acc[i][j] = 0.f;
  int tysw = ty & 7;
  for (int kq = 0; kq < 16; ++kq) {
    float x_[8][4];
#pragma unroll
    for (int i = 0; i < 8; ++i) {
      float4 v = Xl[(ty * 8 + i) * 16 + (kq ^ tysw)];
      x_[i][0] = v.x; x_[i][1] = v.y; x_[i][2] = v.z; x_[i][3] = v.w;
    }
#pragma unroll
    for (int kk = 0; kk < 4; ++kk) {
      int k = kq * 4 + kk;
      float4 w0 = Wl[k * 16 + tx * 2];
      float4 w1 = Wl[k * 16 + tx * 2 + 1];
      float w_[8] = {w0.x, w0.y, w0.z, w0.w, w1.x, w1.y, w1.z, w1.w};
#pragma unroll
      for (int i = 0; i < 8; ++i)
#pragma unroll
        for (int j = 0; j < 8; ++j)
          acc[i][j] = fmaf(x_[i][kk], w_[j], acc[i][j]);
    }
  }
#pragma unroll
  for (int i = 0; i < 8; ++i) {
    int r = row0 + ty * 8 + i;
    if (r < n) {
      float d = dis[r];
      uint4 o;
      o.x = bf16pair(acc[i][0] * d, acc[i][1] * d);
      o.y = bf16pair(acc[i][2] * d, acc[i][3] * d);
      o.z = bf16pair(acc[i][4] * d, acc[i][5] * d);
      o.w = bf16pair(acc[i][6] * d, acc[i][7] * d);
      ((uint4*)Hb)[(size_t)r * 8 + tx] = o;
    }
  }
}

// h2b[n,32 bf16] = bf16( dis ⊙ (P[n,64] @ W2[64,32]) ).  128 thr, 8x4/thread.
__global__ __launch_bounds__(128) void k_gemm32t(const float* __restrict__ P,
                                                 const float* __restrict__ W2,
                                                 const float* __restrict__ dis,
                                                 unsigned* __restrict__ Hb, int n) {
  __shared__ float4 Pl[128 * 16];
  __shared__ float4 Wl[64 * 8];
  int t = threadIdx.x;
  int row0 = blockIdx.x * 128;
#pragma unroll
  for (int j = 0; j < 4; ++j) Wl[t + j * 128] = ((const float4*)W2)[t + j * 128];
#pragma unroll
  for (int j = 0; j < 16; ++j) {
    int v = t + j * 128;
    int r = v >> 4, q = v & 15;
    int gr = row0 + r;
    float4 val = (gr < n) ? ((const float4*)P)[(size_t)gr * 16 + q]
                          : make_float4(0.f, 0.f, 0.f, 0.f);
    Pl[swz(r, q)] = val;
  }
  __syncthreads();
  int tx = t & 7, ty = t >> 3;
  float acc[8][4];
#pragma unroll
  for (int i = 0; i < 8; ++i)
#pragma unroll
    for (int j = 0; j < 4; ++j) acc[i][j] = 0.f;
  int tysw = ty & 7;
  for (int kq = 0; kq < 16; ++kq) {
    float x_[8][4];
#pragma unroll
    for (int i = 0; i < 8; ++i) {
      float4 v = Pl[(ty * 8 + i) * 16 + (kq ^ tysw)];
      x_[i][0] = v.x; x_[i][1] = v.y; x_[i][2] = v.z; x_[i][3] = v.w;
    }
#pragma unroll
    for (int kk = 0; kk < 4; ++kk) {
      int k = kq * 4 + kk;
      float4 w = Wl[k * 8 + tx];
      float w_[4] = {w.x, w.y, w.z, w.w};
#pragma unroll
      for (int i = 0; i < 8; ++i)
#pragma unroll
        for (int j = 0; j < 4; ++j)
          acc[i][j] = fmaf(x_[i][kk], w_[j], acc[i][j]);
    }
  }
#pragma unroll
  for (int i = 0; i < 8; ++i) {
    int r = row0 + ty * 8 + i;
    if (r < n) {
      float d = dis[r];
      uint2 o;
      o.x = bf16pair(acc[i][0] * d, acc[i][1] * d);
      o.y = bf16pair(acc[i][2] * d, acc[i][3] * d);
      ((uint2*)Hb)[(size_t)r * 8 + tx] = o;
    }
  }
}

// ---------------- gathers (bf16 rows, f32 accumulate, NT streaming) ----------------

// One wave per node; lane&15 = uint2 column (4 features), lane>>4 = edge group
// (4 groups), unroll x2 -> 8 row loads in flight.
// p1[i] = relu(dis[i] * (Σ h1b[src] + h1b[i]) + b1)  — f32, NT store.
__global__ __launch_bounds__(256) void k_gather64v(const int* __restrict__ off,
                                                   const int* __restrict__ ssrc,
                                                   const float* __restrict__ dis,
                                                   const uint2* __restrict__ Hb2,
                                                   const float* __restrict__ b1,
                                                   f32x4* __restrict__ P4, int n) {
  int lane = threadIdx.x & 63;
  int q = lane & 15, g = lane >> 4;  // g = 0..3
  int i = blockIdx.x * 4 + (threadIdx.x >> 6);
  if (i >= n) return;
  int beg = off[i], end = off[i + 1];
  float s0 = 0.f, s1 = 0.f, s2 = 0.f, s3 = 0.f;
  if (g == 0) {  // self-loop once
    uint2 v = Hb2[(size_t)i * 16 + q];
    s0 = bf_lo(v.x); s1 = bf_hi(v.x); s2 = bf_lo(v.y); s3 = bf_hi(v.y);
  }
  int e = beg + g;
  for (; e + 4 < end; e += 8) {
    int i0 = __builtin_nontemporal_load(&ssrc[e]);
    int i1 = __builtin_nontemporal_load(&ssrc[e + 4]);
    uint2 v0 = Hb2[(size_t)i0 * 16 + q];
    uint2 v1 = Hb2[(size_t)i1 * 16 + q];
    s0 += bf_lo(v0.x) + bf_lo(v1.x);
    s1 += bf_hi(v0.x) + bf_hi(v1.x);
    s2 += bf_lo(v0.y) + bf_lo(v1.y);
    s3 += bf_hi(v0.y) + bf_hi(v1.y);
  }
  for (; e < end; e += 4) {
    int i0 = __builtin_nontemporal_load(&ssrc[e]);
    uint2 v = Hb2[(size_t)i0 * 16 + q];
    s0 += bf_lo(v.x); s1 += bf_hi(v.x); s2 += bf_lo(v.y); s3 += bf_hi(v.y);
  }
  s0 += __shfl_xor(s0, 16); s1 += __shfl_xor(s1, 16);
  s2 += __shfl_xor(s2, 16); s3 += __shfl_xor(s3, 16);
  s0 += __shfl_xor(s0, 32); s1 += __shfl_xor(s1, 32);
  s2 += __shfl_xor(s2, 32); s3 += __shfl_xor(s3, 32);
  if (lane < 16) {
    float di = dis[i];
    float4 b = ((const float4*)b1)[q];
    f32x4 o;
    o.x = fmaxf(fmaf(di, s0, b.x), 0.f);
    o.y = fmaxf(fmaf(di, s1, b.y), 0.f);
    o.z = fmaxf(fmaf(di, s2, b.z), 0.f);
    o.w = fmaxf(fmaf(di, s3, b.w), 0.f);
    __builtin_nontemporal_store(o, &P4[(size_t)i * 16 + q]);
  }
}

// One wave per node; lane&7 = uint2 column (4 features), lane>>3 = edge group
// (8 groups), unroll x2 -> up to 16 row loads in flight.
// out[i] = relu(dis[i] * (Σ h2b[src] + h2b[i]) + b2)  — f32, NT store.
__global__ __launch_bounds__(256) void k_gather32v(const int* __restrict__ off,
                                                   const int* __restrict__ ssrc,
                                                   const float* __restrict__ dis,
                                                   const uint2* __restrict__ Hb2,
                                                   const float* __restrict__ b2,
                                                   f32x4* __restrict__ out4, int n) {
  int lane = threadIdx.x & 63;
  int q = lane & 7, g = lane >> 3;  // g = 0..7
  int i = blockIdx.x * 4 + (threadIdx.x >> 6);
  if (i >= n) return;
  int beg = off[i], end = off[i + 1];
  float s0 = 0.f, s1 = 0.f, s2 = 0.f, s3 = 0.f;
  if (g == 0) {  // self-loop once
    uint2 v = Hb2[(size_t)i * 8 + q];
    s0 = bf_lo(v.x); s1 = bf_hi(v.x); s2 = bf_lo(v.y); s3 = bf_hi(v.y);
  }
  int e = beg + g;
  for (; e + 8 < end; e += 16) {
    int i0 = __builtin_nontemporal_load(&ssrc[e]);
    int i1 = __builtin_nontemporal_load(&ssrc[e + 8]);
    uint2 v0 = Hb2[(size_t)i0 * 8 + q];
    uint2 v1 = Hb2[(size_t)i1 * 8 + q];
    s0 += bf_lo(v0.x) + bf_lo(v1.x);
    s1 += bf_hi(v0.x) + bf_hi(v1.x);
    s2 += bf_lo(v0.y) + bf_lo(v1.y);
    s3 += bf_hi(v0.y) + bf_hi(v1.y);
  }
  for (; e < end; e += 8) {
    int i0 = __builtin_nontemporal_load(&ssrc[e]);
    uint2 v = Hb2[(size_t)i0 * 8 + q];
    s0 += bf_lo(v.x); s1 += bf_hi(v.x); s2 += bf_lo(v.y); s3 += bf_hi(v.y);
  }
  s0 += __shfl_xor(s0, 8);  s1 += __shfl_xor(s1, 8);
  s2 += __shfl_xor(s2, 8);  s3 += __shfl_xor(s3, 8);
  s0 += __shfl_xor(s0, 16); s1 += __shfl_xor(s1, 16);
  s2 += __shfl_xor(s2, 16); s3 += __shfl_xor(s3, 16);
  s0 += __shfl_xor(s0, 32); s1 += __shfl_xor(s1, 32);
  s2 += __shfl_xor(s2, 32); s3 += __shfl_xor(s3, 32);
  if (lane < 8) {
    float di = dis[i];
    float4 b = ((const float4*)b2)[q];
    f32x4 o;
    o.x = fmaxf(fmaf(di, s0, b.x), 0.f);
    o.y = fmaxf(fmaf(di, s1, b.y), 0.f);
    o.z = fmaxf(fmaf(di, s2, b.z), 0.f);
    o.w = fmaxf(fmaf(di, s3, b.w), 0.f);
    __builtin_nontemporal_store(o, &out4[(size_t)i * 8 + q]);
  }
}

extern "C" void kernel_launch(void* const* d_in, const int* in_sizes, int n_in,
                              void* d_out, int out_size, void* d_ws, size_t ws_size,
                              hipStream_t stream) {
  const float* x  = (const float*)d_in[0];
  const int*   ei = (const int*)d_in[1];
  const float* W1 = (const float*)d_in[2];
  const float* b1 = (const float*)d_in[3];
  const float* W2 = (const float*)d_in[4];
  const float* b2 = (const float*)d_in[5];
  float* out = (float*)d_out;

  const int n = in_sizes[0] / 64;
  const int E = in_sizes[1] / 2;
  const int* src = ei;
  const int* dst = ei + E;
  const int NB = (n + 255) >> 8;

  // 16B-aligned workspace carve-out.
  char* wp = (char*)d_ws;
  auto alloc = [&](size_t bytes) {
    char* p = wp;
    wp += (bytes + 15) & ~(size_t)15;
    return (void*)p;
  };
  unsigned* pairs = (unsigned*)alloc((size_t)E * 4);
  int*      ch    = (int*)alloc(NBMAX * 4);
  int*      cbase = (int*)alloc(NBMAX * 4);
  int*      gcur  = (int*)alloc(NBMAX * 4);
  int*      off   = (int*)alloc(((size_t)n + 1) * 4);
  float*    dis   = (float*)alloc((size_t)n * 4);
  int*      ssrc  = (int*)alloc((size_t)E * 4);
  unsigned* h1b   = (unsigned*)alloc((size_t)n * 64 * 2);  // bf16 [n][64]
  float*    p1    = (float*)alloc((size_t)n * 64 * 4);     // f32  [n][64]
  unsigned* h2b   = (unsigned*)alloc((size_t)n * 32 * 2);  // bf16 [n][32]

  auto cdiv = [](long long a, long long b) { return (unsigned)((a + b - 1) / b); };
  dim3 B(256);

  (void)hipMemsetAsync(ch, 0, (size_t)NBMAX * 4, stream);
  k_coarsehist<<<512, B, 0, stream>>>(dst, ch, E, NB);
  k_scanb     <<<1, 512, 0, stream>>>(ch, cbase, gcur, off, NB, n, E);
  k_binpairs  <<<cdiv(E, BIN_TILE), B, 0, stream>>>(src, dst, gcur, pairs, E, NB);
  k_finesort  <<<NB, 512, 0, stream>>>(pairs, ch, cbase, off, dis, ssrc, n);

  k_gemm64t   <<<cdiv(n, 128), 128, 0, stream>>>(x, W1, dis, h1b, n);
  k_gather64v <<<cdiv(n, 4), B, 0, stream>>>(off, ssrc, dis, (const uint2*)h1b, b1,
                                             (f32x4*)p1, n);
  k_gemm32t   <<<cdiv(n, 128), 128, 0, stream>>>(p1, W2, dis, h2b, n);
  k_gather32v <<<cdiv(n, 4), B, 0, stream>>>(off, ssrc, dis, (const uint2*)h2b, b2,
                                             (f32x4*)out, n);
}

// Round 14
// 200.139 us; speedup vs baseline: 1.3095x; 1.0794x over previous
//
#include <hip/hip_runtime.h>

// 2-layer GCN on MI355X — gather formulation, two-level counting sort,
// dis-prescaled bf16 features, tiled GEMMs, deep-MLP gathers.
// (R7-best configuration: no NT hints; 512-thread finesort; BIN_TILE 4096.)
//
// out = relu(Ahat @ relu(Ahat @ (x@W1) + b1) @ W2 + b2),
// Ahat = D^-1/2 (A+I) D^-1/2.
//
// Pipeline:
//  1. counting sort (packed uint pairs) -> off[], dis[], ssrc[]
//  2. k_gemm64t  : h1b = bf16( dis ⊙ (x @ W1) )         [tiled 8x8/thread]
//  3. k_gather64v: p1 = relu(dis[i]*(Σ h1b[src] + h1b[i]) + b1)   (f32)
//  4. k_gemm32t  : h2b = bf16( dis ⊙ (p1 @ W2) )        [tiled 8x4/thread]
//  5. k_gather32v: out = relu(dis[i]*(Σ h2b[src] + h2b[i]) + b2)  (f32)

#define NBMAX 512  // coarse buckets (dst>>8); requires n < 2^17
#define BIN_TILE 4096

// ---- bf16 pack/unpack (round-to-nearest-even) ----
__device__ __forceinline__ unsigned bf16pair(float a, float b) {
  unsigned ua = __float_as_uint(a), ub = __float_as_uint(b);
  ua = (ua + 0x7fffu + ((ua >> 16) & 1u)) >> 16;
  ub = (ub + 0x7fffu + ((ub >> 16) & 1u)) >> 16;
  return ua | (ub << 16);
}
__device__ __forceinline__ float bf_lo(unsigned v) { return __uint_as_float(v << 16); }
__device__ __forceinline__ float bf_hi(unsigned v) { return __uint_as_float(v & 0xffff0000u); }

// ---------------- sort pipeline ----------------

__global__ __launch_bounds__(256) void k_coarsehist(const int* __restrict__ dst,
                                                    int* __restrict__ ch,
                                                    int E, int NB) {
  __shared__ int lh[NBMAX];
  int t = threadIdx.x;
  lh[t] = 0; lh[t + 256] = 0;
  __syncthreads();
  for (int e = blockIdx.x * 256 + t; e < E; e += gridDim.x * 256)
    atomicAdd(&lh[dst[e] >> 8], 1);
  __syncthreads();
  for (int b = t; b < NB; b += 256) {
    int c = lh[b];
    if (c) atomicAdd(&ch[b], c);
  }
}

__global__ __launch_bounds__(512) void k_scanb(const int* __restrict__ ch,
                                               int* __restrict__ cbase,
                                               int* __restrict__ gcur,
                                               int* __restrict__ off,
                                               int NB, int n, int E) {
  __shared__ int lds[512];
  int t = threadIdx.x;
  int v = (t < NB) ? ch[t] : 0;
  lds[t] = v;
  __syncthreads();
  for (int d = 1; d < 512; d <<= 1) {
    int u = (t >= d) ? lds[t - d] : 0;
    __syncthreads();
    lds[t] += u;
    __syncthreads();
  }
  if (t < NB) {
    int exc = lds[t] - v;
    cbase[t] = exc;
    gcur[t]  = exc;
  }
  if (t == 0) off[n] = E;
}

// Tile-phased binning: packed (src<<8 | dst&255) runs per coarse bucket.
__global__ __launch_bounds__(256) void k_binpairs(const int* __restrict__ src,
                                                  const int* __restrict__ dst,
                                                  int* __restrict__ gcur,
                                                  unsigned* __restrict__ pairs,
                                                  int E, int NB) {
  __shared__ int lcnt[NBMAX], gbase[NBMAX];
  int t = threadIdx.x;
  int tile0 = blockIdx.x * BIN_TILE;
  lcnt[t] = 0; lcnt[t + 256] = 0;
  __syncthreads();
#pragma unroll
  for (int j = 0; j < BIN_TILE / 256; ++j) {
    int e = tile0 + j * 256 + t;
    if (e < E) atomicAdd(&lcnt[dst[e] >> 8], 1);
  }
  __syncthreads();
  for (int b = t; b < NB; b += 256) {
    int c = lcnt[b];
    if (c) gbase[b] = atomicAdd(&gcur[b], c);
    lcnt[b] = 0;
  }
  __syncthreads();
#pragma unroll
  for (int j = 0; j < BIN_TILE / 256; ++j) {
    int e = tile0 + j * 256 + t;
    if (e < E) {
      int dv = dst[e];
      int b  = dv >> 8;
      int slot = atomicAdd(&lcnt[b], 1);
      pairs[gbase[b] + slot] = ((unsigned)src[e] << 8) | (unsigned)(dv & 255);
    }
  }
}

// One block (512 thr) per coarse bucket: fine sort by dst&255.
__global__ __launch_bounds__(512) void k_finesort(const unsigned* __restrict__ pairs,
                                                  const int* __restrict__ ch,
                                                  const int* __restrict__ cbase,
                                                  int* __restrict__ off,
                                                  float* __restrict__ dis,
                                                  int* __restrict__ ssrc, int n) {
  __shared__ int hist[256], lcur[256], wsum[4];
  __shared__ int sbuf[8192];
  int b = blockIdx.x;
  int node0 = b << 8;
  int nn = min(256, n - node0);
  int cnt = ch[b], base = cbase[b];
  int t = threadIdx.x;
  if (t < 256) hist[t] = 0;
  __syncthreads();
  for (int e = t; e < cnt; e += 512)
    atomicAdd(&hist[pairs[base + e] & 255u], 1);
  __syncthreads();
  int c = 0, inc = 0;
  if (t < 256) {
    c = hist[t];
    int lane = t & 63;
    inc = c;
#pragma unroll
    for (int d = 1; d < 64; d <<= 1) {
      int u = __shfl_up(inc, d);
      if (lane >= d) inc += u;
    }
    if (lane == 63) wsum[t >> 6] = inc;
  }
  __syncthreads();
  if (t < 256) {
    int wv = t >> 6;
    int pre = 0;
    for (int w = 0; w < wv; ++w) pre += wsum[w];
    int exc = pre + inc - c;
    if (t < nn) {
      off[node0 + t] = base + exc;
      dis[node0 + t] = rsqrtf((float)(c + 1));
    }
    lcur[t] = exc;
  }
  __syncthreads();
  bool inlds = (cnt <= 8192);
  for (int e = t; e < cnt; e += 512) {
    unsigned p = pairs[base + e];
    int slot = atomicAdd(&lcur[p & 255u], 1);
    int sv = (int)(p >> 8);
    if (inlds) sbuf[slot] = sv;
    else       ssrc[base + slot] = sv;
  }
  __syncthreads();
  if (inlds)
    for (int e = t; e < cnt; e += 512) ssrc[base + e] = sbuf[e];
}

// ---------------- tiled GEMMs ----------------

__device__ __forceinline__ int swz(int r, int q) {
  return r * 16 + (q ^ ((r >> 3) & 7));
}

// h1b[n,64 bf16] = bf16( dis ⊙ (X[n,64] @ W[64,64]) ).  128 thr, 8x8/thread.
__global__ __launch_bounds__(128) void k_gemm64t(const float* __restrict__ X,
                                                 const float* __restrict__ W,
                                                 const float* __restrict__ dis,
                                                 unsigned* __restrict__ Hb, int n) {
  __shared__ float4 Xl[128 * 16];
  __shared__ float4 Wl[64 * 16];
  int t = threadIdx.x;
  int row0 = blockIdx.x * 128;
#pragma unroll
  for (int j = 0; j < 8; ++j) Wl[t + j * 128] = ((const float4*)W)[t + j * 128];
#pragma unroll
  for (int j = 0; j < 16; ++j) {
    int v = t + j * 128;
    int r = v >> 4, q = v & 15;
    int gr = row0 + r;
    float4 val = (gr < n) ? ((const float4*)X)[(size_t)gr * 16 + q]
                          : make_float4(0.f, 0.f, 0.f, 0.f);
    Xl[swz(r, q)] = val;
  }
  __syncthreads();
  int tx = t & 7, ty = t >> 3;
  float acc[8][8];
#pragma unroll
  for (int i = 0; i < 8; ++i)
#pragma unroll
    for (int j = 0; j < 8; ++j) acc[i][j] = 0.f;
  int tysw = ty & 7;
  for (int kq = 0; kq < 16; ++kq) {
    float x_[8][4];
#pragma unroll
    for (int i = 0; i < 8; ++i) {
      float4 v = Xl[(ty * 8 + i) * 16 + (kq ^ tysw)];
      x_[i][0] = v.x; x_[i][1] = v.y; x_[i][2] = v.z; x_[i][3] = v.w;
    }
#pragma unroll
    for (int kk = 0; kk < 4; ++kk) {
      int k = kq * 4 + kk;
      float4 w0 = Wl[k * 16 + tx * 2];
      float4 w1 = Wl[k * 16 + tx * 2 + 1];
      float w_[8] = {w0.x, w0.y, w0.z, w0.w, w1.x, w1.y, w1.z, w1.w};
#pragma unroll
      for (int i = 0; i < 8; ++i)
#pragma unroll
        for (int j = 0; j < 8; ++j)
          acc[i][j] = fmaf(x_[i][kk], w_[j], acc[i][j]);
    }
  }
#pragma unroll
  for (int i = 0; i < 8; ++i) {
    int r = row0 + ty * 8 + i;
    if (r < n) {
      float d = dis[r];
      uint4 o;
      o.x = bf16pair(acc[i][0] * d, acc[i][1] * d);
      o.y = bf16pair(acc[i][2] * d, acc[i][3] * d);
      o.z = bf16pair(acc[i][4] * d, acc[i][5] * d);
      o.w = bf16pair(acc[i][6] * d, acc[i][7] * d);
      ((uint4*)Hb)[(size_t)r * 8 + tx] = o;
    }
  }
}

// h2b[n,32 bf16] = bf16( dis ⊙ (P[n,64] @ W2[64,32]) ).  128 thr, 8x4/thread.
__global__ __launch_bounds__(128) void k_gemm32t(const float* __restrict__ P,
                                                 const float* __restrict__ W2,
                                                 const float* __restrict__ dis,
                                                 unsigned* __restrict__ Hb, int n) {
  __shared__ float4 Pl[128 * 16];
  __shared__ float4 Wl[64 * 8];
  int t = threadIdx.x;
  int row0 = blockIdx.x * 128;
#pragma unroll
  for (int j = 0; j < 4; ++j) Wl[t + j * 128] = ((const float4*)W2)[t + j * 128];
#pragma unroll
  for (int j = 0; j < 16; ++j) {
    int v = t + j * 128;
    int r = v >> 4, q = v & 15;
    int gr = row0 + r;
    float4 val = (gr < n) ? ((const float4*)P)[(size_t)gr * 16 + q]
                          : make_float4(0.f, 0.f, 0.f, 0.f);
    Pl[swz(r, q)] = val;
  }
  __syncthreads();
  int tx = t & 7, ty = t >> 3;
  float acc[8][4];
#pragma unroll
  for (int i = 0; i < 8; ++i)
#pragma unroll
    for (int j = 0; j < 4; ++j) acc[i][j] = 0.f;
  int tysw = ty & 7;
  for (int kq = 0; kq < 16; ++kq) {
    float x_[8][4];
#pragma unroll
    for (int i = 0; i < 8; ++i) {
      float4 v = Pl[(ty * 8 + i) * 16 + (kq ^ tysw)];
      x_[i][0] = v.x; x_[i][1] = v.y; x_[i][2] = v.z; x_[i][3] = v.w;
    }
#pragma unroll
    for (int kk = 0; kk < 4; ++kk) {
      int k = kq * 4 + kk;
      float4 w = Wl[k * 8 + tx];
      float w_[4] = {w.x, w.y, w.z, w.w};
#pragma unroll
      for (int i = 0; i < 8; ++i)
#pragma unroll
        for (int j = 0; j < 4; ++j)
          acc[i][j] = fmaf(x_[i][kk], w_[j], acc[i][j]);
    }
  }
#pragma unroll
  for (int i = 0; i < 8; ++i) {
    int r = row0 + ty * 8 + i;
    if (r < n) {
      float d = dis[r];
      uint2 o;
      o.x = bf16pair(acc[i][0] * d, acc[i][1] * d);
      o.y = bf16pair(acc[i][2] * d, acc[i][3] * d);
      ((uint2*)Hb)[(size_t)r * 8 + tx] = o;
    }
  }
}

// ---------------- gathers (bf16 rows, f32 accumulate, deep MLP) ----------------

// One wave per node; lane&15 = uint2 column (4 features), lane>>4 = edge group
// (4 groups), unroll x2 -> 8 row loads in flight.
// p1[i] = relu(dis[i] * (Σ h1b[src] + h1b[i]) + b1)  — f32 output.
__global__ __launch_bounds__(256) void k_gather64v(const int* __restrict__ off,
                                                   const int* __restrict__ ssrc,
                                                   const float* __restrict__ dis,
                                                   const uint2* __restrict__ Hb2,
                                                   const float* __restrict__ b1,
                                                   float4* __restrict__ P4, int n) {
  int lane = threadIdx.x & 63;
  int q = lane & 15, g = lane >> 4;  // g = 0..3
  int i = blockIdx.x * 4 + (threadIdx.x >> 6);
  if (i >= n) return;
  int beg = off[i], end = off[i + 1];
  float s0 = 0.f, s1 = 0.f, s2 = 0.f, s3 = 0.f;
  if (g == 0) {  // self-loop once
    uint2 v = Hb2[(size_t)i * 16 + q];
    s0 = bf_lo(v.x); s1 = bf_hi(v.x); s2 = bf_lo(v.y); s3 = bf_hi(v.y);
  }
  int e = beg + g;
  for (; e + 4 < end; e += 8) {
    uint2 v0 = Hb2[(size_t)ssrc[e]     * 16 + q];
    uint2 v1 = Hb2[(size_t)ssrc[e + 4] * 16 + q];
    s0 += bf_lo(v0.x) + bf_lo(v1.x);
    s1 += bf_hi(v0.x) + bf_hi(v1.x);
    s2 += bf_lo(v0.y) + bf_lo(v1.y);
    s3 += bf_hi(v0.y) + bf_hi(v1.y);
  }
  for (; e < end; e += 4) {
    uint2 v = Hb2[(size_t)ssrc[e] * 16 + q];
    s0 += bf_lo(v.x); s1 += bf_hi(v.x); s2 += bf_lo(v.y); s3 += bf_hi(v.y);
  }
  s0 += __shfl_xor(s0, 16); s1 += __shfl_xor(s1, 16);
  s2 += __shfl_xor(s2, 16); s3 += __shfl_xor(s3, 16);
  s0 += __shfl_xor(s0, 32); s1 += __shfl_xor(s1, 32);
  s2 += __shfl_xor(s2, 32); s3 += __shfl_xor(s3, 32);
  if (lane < 16) {
    float di = dis[i];
    float4 b = ((const float4*)b1)[q];
    float4 o;
    o.x = fmaxf(fmaf(di, s0, b.x), 0.f);
    o.y = fmaxf(fmaf(di, s1, b.y), 0.f);
    o.z = fmaxf(fmaf(di, s2, b.z), 0.f);
    o.w = fmaxf(fmaf(di, s3, b.w), 0.f);
    P4[(size_t)i * 16 + q] = o;
  }
}

// One wave per node; lane&7 = uint2 column (4 features), lane>>3 = edge group
// (8 groups), unroll x2 -> up to 16 row loads in flight.
// out[i] = relu(dis[i] * (Σ h2b[src] + h2b[i]) + b2)  — f32 output.
__global__ __launch_bounds__(256) void k_gather32v(const int* __restrict__ off,
                                                   const int* __restrict__ ssrc,
                                                   const float* __restrict__ dis,
                                                   const uint2* __restrict__ Hb2,
                                                   const float* __restrict__ b2,
                                                   float4* __restrict__ out4, int n) {
  int lane = threadIdx.x & 63;
  int q = lane & 7, g = lane >> 3;  // g = 0..7
  int i = blockIdx.x * 4 + (threadIdx.x >> 6);
  if (i >= n) return;
  int beg = off[i], end = off[i + 1];
  float s0 = 0.f, s1 = 0.f, s2 = 0.f, s3 = 0.f;
  if (g == 0) {  // self-loop once
    uint2 v = Hb2[(size_t)i * 8 + q];
    s0 = bf_lo(v.x); s1 = bf_hi(v.x); s2 = bf_lo(v.y); s3 = bf_hi(v.y);
  }
  int e = beg + g;
  for (; e + 8 < end; e += 16) {
    uint2 v0 = Hb2[(size_t)ssrc[e]     * 8 + q];
    uint2 v1 = Hb2[(size_t)ssrc[e + 8] * 8 + q];
    s0 += bf_lo(v0.x) + bf_lo(v1.x);
    s1 += bf_hi(v0.x) + bf_hi(v1.x);
    s2 += bf_lo(v0.y) + bf_lo(v1.y);
    s3 += bf_hi(v0.y) + bf_hi(v1.y);
  }
  for (; e < end; e += 8) {
    uint2 v = Hb2[(size_t)ssrc[e] * 8 + q];
    s0 += bf_lo(v.x); s1 += bf_hi(v.x); s2 += bf_lo(v.y); s3 += bf_hi(v.y);
  }
  s0 += __shfl_xor(s0, 8);  s1 += __shfl_xor(s1, 8);
  s2 += __shfl_xor(s2, 8);  s3 += __shfl_xor(s3, 8);
  s0 += __shfl_xor(s0, 16); s1 += __shfl_xor(s1, 16);
  s2 += __shfl_xor(s2, 16); s3 += __shfl_xor(s3, 16);
  s0 += __shfl_xor(s0, 32); s1 += __shfl_xor(s1, 32);
  s2 += __shfl_xor(s2, 32); s3 += __shfl_xor(s3, 32);
  if (lane < 8) {
    float di = dis[i];
    float4 b = ((const float4*)b2)[q];
    float4 o;
    o.x = fmaxf(fmaf(di, s0, b.x), 0.f);
    o.y = fmaxf(fmaf(di, s1, b.y), 0.f);
    o.z = fmaxf(fmaf(di, s2, b.z), 0.f);
    o.w = fmaxf(fmaf(di, s3, b.w), 0.f);
    out4[(size_t)i * 8 + q] = o;
  }
}

extern "C" void kernel_launch(void* const* d_in, const int* in_sizes, int n_in,
                              void* d_out, int out_size, void* d_ws, size_t ws_size,
                              hipStream_t stream) {
  const float* x  = (const float*)d_in[0];
  const int*   ei = (const int*)d_in[1];
  const float* W1 = (const float*)d_in[2];
  const float* b1 = (const float*)d_in[3];
  const float* W2 = (const float*)d_in[4];
  const float* b2 = (const float*)d_in[5];
  float* out = (float*)d_out;

  const int n = in_sizes[0] / 64;
  const int E = in_sizes[1] / 2;
  const int* src = ei;
  const int* dst = ei + E;
  const int NB = (n + 255) >> 8;

  // 16B-aligned workspace carve-out.
  char* wp = (char*)d_ws;
  auto alloc = [&](size_t bytes) {
    char* p = wp;
    wp += (bytes + 15) & ~(size_t)15;
    return (void*)p;
  };
  unsigned* pairs = (unsigned*)alloc((size_t)E * 4);
  int*      ch    = (int*)alloc(NBMAX * 4);
  int*      cbase = (int*)alloc(NBMAX * 4);
  int*      gcur  = (int*)alloc(NBMAX * 4);
  int*      off   = (int*)alloc(((size_t)n + 1) * 4);
  float*    dis   = (float*)alloc((size_t)n * 4);
  int*      ssrc  = (int*)alloc((size_t)E * 4);
  unsigned* h1b   = (unsigned*)alloc((size_t)n * 64 * 2);  // bf16 [n][64]
  float*    p1    = (float*)alloc((size_t)n * 64 * 4);     // f32  [n][64]
  unsigned* h2b   = (unsigned*)alloc((size_t)n * 32 * 2);  // bf16 [n][32]

  auto cdiv = [](long long a, long long b) { return (unsigned)((a + b - 1) / b); };
  dim3 B(256);

  (void)hipMemsetAsync(ch, 0, (size_t)NBMAX * 4, stream);
  k_coarsehist<<<512, B, 0, stream>>>(dst, ch, E, NB);
  k_scanb     <<<1, 512, 0, stream>>>(ch, cbase, gcur, off, NB, n, E);
  k_binpairs  <<<cdiv(E, BIN_TILE), B, 0, stream>>>(src, dst, gcur, pairs, E, NB);
  k_finesort  <<<NB, 512, 0, stream>>>(pairs, ch, cbase, off, dis, ssrc, n);

  k_gemm64t   <<<cdiv(n, 128), 128, 0, stream>>>(x, W1, dis, h1b, n);
  k_gather64v <<<cdiv(n, 4), B, 0, stream>>>(off, ssrc, dis, (const uint2*)h1b, b1,
                                             (float4*)p1, n);
  k_gemm32t   <<<cdiv(n, 128), 128, 0, stream>>>(p1, W2, dis, h2b, n);
  k_gather32v <<<cdiv(n, 4), B, 0, stream>>>(off, ssrc, dis, (const uint2*)h2b, b2,
                                             (float4*)out, n);
}